// Round 6
// baseline (336.897 us; speedup 1.0000x reference)
//
#include <hip/hip_runtime.h>
#include <hip/hip_bf16.h>

typedef __attribute__((ext_vector_type(8))) short bf16x8;
typedef __attribute__((ext_vector_type(4))) float f32x4;

#define B_SZ   1024
#define T_SZ   128
#define L_SZ   256
#define F_SZ   784
#define M_TOT  (B_SZ * T_SZ)            // 131072
#define BK     32
#define KSTEPS 25                       // ceil(784/32), tail zero-padded

#define WPRE_ELEMS (KSTEPS * 4 * L_SZ)  // 25600 bf16x8 elements
#define WPRE_BYTES (WPRE_ELEMS * 16)    // 409600
#define CDIFF_ELEMS (T_SZ * L_SZ)       // 32768
#define WS_NEED (WPRE_BYTES + CDIFF_ELEMS * 4)

__device__ __forceinline__ unsigned short f2bf(float f) {
    __hip_bfloat16 h = __float2bfloat16(f);   // RTNE
    return *reinterpret_cast<unsigned short*>(&h);
}

// ---------------- prep: W -> bf16 MFMA-fragment layout; cdiff = c0 - c1 ----
// wpre[ks][kgrp][leaf] : bf16x8 = W[leaf][ks*32+kgrp*8 .. +8), 0-padded tail
__global__ __launch_bounds__(256) void dn_prep(
    const float* __restrict__ W, const float* __restrict__ contrib,
    unsigned short* __restrict__ wpre, float* __restrict__ cdiff)
{
    const int gid = blockIdx.x * 256 + threadIdx.x;
    if (gid < WPRE_ELEMS) {
        const int leaf = gid & 255;
        const int kg   = (gid >> 8) & 3;
        const int ks   = gid >> 10;
        const int k0   = ks * BK + kg * 8;
        bf16x8 v;
        #pragma unroll
        for (int j = 0; j < 8; ++j) {
            const int k = k0 + j;
            const float f = (k < F_SZ) ? W[(size_t)leaf * F_SZ + k] : 0.f;
            v[j] = (short)f2bf(f);
        }
        *reinterpret_cast<bf16x8*>(wpre + (size_t)gid * 8) = v;
    } else {
        const int cid = gid - WPRE_ELEMS;
        if (cid < CDIFF_ELEMS)
            cdiff[cid] = contrib[(size_t)cid * 2] - contrib[(size_t)cid * 2 + 1];
    }
}

// ---------------- v5: streaming MFMA, PINNED register pipeline -------------
// Wave tile 32 rows x 64 cols; 4 waves/block; grid 4096 = 1024 rowGroups x
// 4 col-quarters, quarters of one rowGroup on the SAME XCD (bid&7 fixed).
// Pipeline: X loads 2 iters ahead (HBM ~900cy), W loads 1 iter ahead (L2
// ~200cy), rotating compile-time-indexed stage regs. sched_barrier(0) after
// the issue block makes each unrolled iter a hard scheduling region, so the
// compiler CANNOT sink loads to their use (v3/v4 failure, VGPR=76) and its
// waitcnt pass emits counted vmcnt (stages k+1/k+2 stay in flight while we
// wait on stage k).
__global__ __launch_bounds__(256, 3) void dn_fused5(
    const float* __restrict__ x, const unsigned short* __restrict__ wpre,
    const float* __restrict__ bias, const float* __restrict__ cdiff,
    float* __restrict__ out)
{
    const int tid  = threadIdx.x;
    const int lane = tid & 63;
    const int wid  = tid >> 6;          // 0..3
    const int lr   = lane & 15;
    const int kseg = lane >> 4;         // 0..3

    const int bid = blockIdx.x;
    const int s   = bid >> 3;
    const int q   = s & 3;                        // col quarter 0..3
    const int rg  = (bid & 7) + 8 * (s >> 2);     // rowGroup 0..1023
    const int rowBase = rg * 128 + wid * 32;
    const int colBase = q * 64;

    const float* xp0 = x + (size_t)(rowBase + lr) * F_SZ + kseg * 8;
    const float* xp1 = xp0 + (size_t)16 * F_SZ;
    const unsigned short* wp = wpre + ((size_t)kseg * L_SZ + colBase + lr) * 8;

    f32x4 acc[2][4];
    #pragma unroll
    for (int mi = 0; mi < 2; ++mi)
        #pragma unroll
        for (int ni = 0; ni < 4; ++ni)
            acc[mi][ni] = (f32x4){0.f, 0.f, 0.f, 0.f};

    // rotating pipeline stages — compile-time indices only (full unroll)
    f32x4  xs[3][4];   // X: 2 iterations ahead
    bf16x8 ws[2][4];   // W: 1 iteration ahead

    // Tail p==24: k=768+kseg*8 valid only for kseg<2; wpre is zero-padded
    // there so values are don't-care — clamp the ADDRESS back in-bounds.
    #define ISSUE_X(p)                                                        \
        do {                                                                  \
            const int _st  = (p) % 3;                                         \
            const int _off = ((p) < 24 || kseg < 2) ? (p) * 32 : -(kseg * 8); \
            xs[_st][0] = *reinterpret_cast<const f32x4*>(xp0 + _off);         \
            xs[_st][1] = *reinterpret_cast<const f32x4*>(xp0 + _off + 4);     \
            xs[_st][2] = *reinterpret_cast<const f32x4*>(xp1 + _off);         \
            xs[_st][3] = *reinterpret_cast<const f32x4*>(xp1 + _off + 4);     \
        } while (0)

    #define ISSUE_W(p)                                                        \
        do {                                                                  \
            const int _st = (p) % 2;                                          \
            _Pragma("unroll")                                                 \
            for (int _ni = 0; _ni < 4; ++_ni)                                 \
                ws[_st][_ni] = *reinterpret_cast<const bf16x8*>(              \
                    wp + (size_t)(p) * 8192 + _ni * 128);                     \
        } while (0)

    // prologue: X two ahead, W one ahead
    ISSUE_X(0);
    ISSUE_X(1);
    ISSUE_W(0);
    __builtin_amdgcn_sched_barrier(0);

    #pragma unroll
    for (int k = 0; k < KSTEPS; ++k) {
        if (k + 2 < KSTEPS) ISSUE_X(k + 2);
        if (k + 1 < KSTEPS) ISSUE_W(k + 1);
        __builtin_amdgcn_sched_barrier(0);

        bf16x8 a0, a1;
        #pragma unroll
        for (int j = 0; j < 4; ++j) {
            a0[j]     = (short)f2bf(xs[k % 3][0][j]);
            a0[4 + j] = (short)f2bf(xs[k % 3][1][j]);
            a1[j]     = (short)f2bf(xs[k % 3][2][j]);
            a1[4 + j] = (short)f2bf(xs[k % 3][3][j]);
        }

        #pragma unroll
        for (int ni = 0; ni < 4; ++ni) {
            acc[0][ni] = __builtin_amdgcn_mfma_f32_16x16x32_bf16(a0, ws[k % 2][ni], acc[0][ni], 0, 0, 0);
            acc[1][ni] = __builtin_amdgcn_mfma_f32_16x16x32_bf16(a1, ws[k % 2][ni], acc[1][ni], 0, 0, 0);
        }
        __builtin_amdgcn_sched_barrier(0);
    }
    #undef ISSUE_X
    #undef ISSUE_W

    // epilogue: sp = clip(acc + b); gini = 1 + 2 s (1-s), s = sigmoid(sp*cdiff)
    const size_t GOFF = (size_t)M_TOT * L_SZ;
    #pragma unroll
    for (int ni = 0; ni < 4; ++ni) {
        const int col = colBase + ni * 16 + lr;
        const float bb = bias[col];
        #pragma unroll
        for (int mi = 0; mi < 2; ++mi) {
            #pragma unroll
            for (int r = 0; r < 4; ++r) {
                const int m = rowBase + mi * 16 + kseg * 4 + r;   // C/D row map
                const int t = m & (T_SZ - 1);
                float v  = acc[mi][ni][r] + bb;
                float sp = fminf(fmaxf(v, -1.f), 1.f);
                const float d  = sp * cdiff[t * L_SZ + col];
                const float ed = __expf(d);
                const float s2 = ed / (1.f + ed);
                const float g  = fmaf(2.f * s2, 1.f - s2, 1.f);
                const size_t o = (size_t)m * L_SZ + col;
                out[o]        = sp;
                out[GOFF + o] = g;
            }
        }
    }
}

// ---------------- v1 fallback (no workspace needed) ------------------------
__global__ __launch_bounds__(512) void dn_fused_v1(
    const float* __restrict__ x, const float* __restrict__ W,
    const float* __restrict__ bias, const float* __restrict__ contrib,
    float* __restrict__ out)
{
    __shared__ bf16x8 As[4][128];
    __shared__ bf16x8 Bs[4][L_SZ];

    const int tid    = threadIdx.x;
    const int lane   = tid & 63;
    const int wid    = tid >> 6;
    const int waveM  = wid >> 2;
    const int waveN  = wid & 3;
    const int blkRow = blockIdx.x * 128;
    const int ar = tid >> 2;
    const int ak = (tid & 3) * 8;
    const int wr = tid >> 1;
    const int wk = (tid & 1) * 16;
    const int laneRow = lane & 15;
    const int kgrp    = lane >> 4;

    f32x4 acc[4][4];
    #pragma unroll
    for (int i = 0; i < 4; ++i)
        #pragma unroll
        for (int j = 0; j < 4; ++j)
            acc[i][j] = (f32x4){0.f, 0.f, 0.f, 0.f};

    const float* xrow = x + (size_t)(blkRow + ar) * F_SZ;
    const float* wrow = W + (size_t)wr * F_SZ;
    const f32x4 zf = {0.f, 0.f, 0.f, 0.f};

    f32x4 xa0 = *reinterpret_cast<const f32x4*>(xrow + ak);
    f32x4 xa1 = *reinterpret_cast<const f32x4*>(xrow + ak + 4);
    f32x4 wa0 = *reinterpret_cast<const f32x4*>(wrow + wk);
    f32x4 wa1 = *reinterpret_cast<const f32x4*>(wrow + wk + 4);
    f32x4 wa2 = *reinterpret_cast<const f32x4*>(wrow + wk + 8);
    f32x4 wa3 = *reinterpret_cast<const f32x4*>(wrow + wk + 12);

    for (int ks = 0; ks < KSTEPS; ++ks) {
        bf16x8 av, wv0, wv1;
        #pragma unroll
        for (int j = 0; j < 4; ++j) {
            av[j]      = (short)f2bf(xa0[j]);
            av[4 + j]  = (short)f2bf(xa1[j]);
            wv0[j]     = (short)f2bf(wa0[j]);
            wv0[4 + j] = (short)f2bf(wa1[j]);
            wv1[j]     = (short)f2bf(wa2[j]);
            wv1[4 + j] = (short)f2bf(wa3[j]);
        }
        As[ak >> 3][ar] = av;
        Bs[wk >> 3][wr] = wv0;
        Bs[(wk >> 3) + 1][wr] = wv1;
        __syncthreads();

        if (ks + 1 < KSTEPS) {
            const int kb = (ks + 1) * BK;
            if (kb + ak < F_SZ) {
                xa0 = *reinterpret_cast<const f32x4*>(xrow + kb + ak);
                xa1 = *reinterpret_cast<const f32x4*>(xrow + kb + ak + 4);
            } else { xa0 = zf; xa1 = zf; }
            if (kb + wk < F_SZ) {
                wa0 = *reinterpret_cast<const f32x4*>(wrow + kb + wk);
                wa1 = *reinterpret_cast<const f32x4*>(wrow + kb + wk + 4);
                wa2 = *reinterpret_cast<const f32x4*>(wrow + kb + wk + 8);
                wa3 = *reinterpret_cast<const f32x4*>(wrow + kb + wk + 12);
            } else { wa0 = zf; wa1 = zf; wa2 = zf; wa3 = zf; }
        }

        bf16x8 af[4], bfv[4];
        #pragma unroll
        for (int mi = 0; mi < 4; ++mi)
            af[mi] = As[kgrp][waveM * 64 + mi * 16 + laneRow];
        #pragma unroll
        for (int ni = 0; ni < 4; ++ni)
            bfv[ni] = Bs[kgrp][waveN * 64 + ni * 16 + laneRow];
        #pragma unroll
        for (int mi = 0; mi < 4; ++mi)
            #pragma unroll
            for (int ni = 0; ni < 4; ++ni)
                acc[mi][ni] = __builtin_amdgcn_mfma_f32_16x16x32_bf16(
                    af[mi], bfv[ni], acc[mi][ni], 0, 0, 0);
        __syncthreads();
    }

    const size_t GOFF  = (size_t)M_TOT * L_SZ;
    const int    rbase = waveM * 64 + (lane >> 4) * 4;
    const int    cbase = waveN * 64 + laneRow;
    #pragma unroll
    for (int ni = 0; ni < 4; ++ni) {
        const int col = cbase + ni * 16;
        const float bb = bias[col];
        #pragma unroll
        for (int mi = 0; mi < 4; ++mi) {
            #pragma unroll
            for (int r = 0; r < 4; ++r) {
                const int m = blkRow + rbase + mi * 16 + r;
                const int t = m & (T_SZ - 1);
                float v  = acc[mi][ni][r] + bb;
                float sp = fminf(fmaxf(v, -1.f), 1.f);
                const float* cp = contrib + (size_t)(t * L_SZ + col) * 2;
                const float d  = sp * (cp[0] - cp[1]);
                const float ed = __expf(d);
                const float s  = ed / (1.f + ed);
                const float g  = fmaf(2.f * s, 1.f - s, 1.f);
                const size_t o = (size_t)m * L_SZ + col;
                out[o]        = sp;
                out[GOFF + o] = g;
            }
        }
    }
}

extern "C" void kernel_launch(void* const* d_in, const int* in_sizes, int n_in,
                              void* d_out, int out_size, void* d_ws, size_t ws_size,
                              hipStream_t stream) {
    const float* x       = (const float*)d_in[0];
    const float* W       = (const float*)d_in[1];
    const float* bias    = (const float*)d_in[2];
    const float* contrib = (const float*)d_in[3];
    float* out = (float*)d_out;

    if (ws_size >= (size_t)WS_NEED && d_ws != nullptr) {
        unsigned short* wpre  = (unsigned short*)d_ws;
        float*          cdiff = (float*)((char*)d_ws + WPRE_BYTES);
        const int prep_threads = WPRE_ELEMS + CDIFF_ELEMS;
        dn_prep<<<(prep_threads + 255) / 256, 256, 0, stream>>>(W, contrib, wpre, cdiff);
        dn_fused5<<<4096, 256, 0, stream>>>(x, wpre, bias, cdiff, out);
    } else {
        dn_fused_v1<<<M_TOT / 128, 512, 0, stream>>>(x, W, bias, contrib, out);
    }
}

// Round 7
// 271.834 us; speedup vs baseline: 1.2393x; 1.2393x over previous
//
#include <hip/hip_runtime.h>
#include <hip/hip_bf16.h>

typedef __attribute__((ext_vector_type(8))) short bf16x8;
typedef __attribute__((ext_vector_type(4))) float f32x4;

#define B_SZ   1024
#define T_SZ   128
#define L_SZ   256
#define F_SZ   784
#define M_TOT  (B_SZ * T_SZ)            // 131072
#define BK     32
#define KSTEPS 25                       // ceil(784/32), tail zero-padded
#define KCHUNKS 100                     // KSTEPS*4 chunks of 8 k-values
#define BROWS  32                       // rows per block

#define WPRE_ELEMS (KSTEPS * 4 * L_SZ)  // 25600 bf16x8 elements
#define WPRE_BYTES (WPRE_ELEMS * 16)    // 409600
#define CDIFF_ELEMS (T_SZ * L_SZ)       // 32768
#define WS_NEED (WPRE_BYTES + CDIFF_ELEMS * 4)

__device__ __forceinline__ unsigned short f2bf(float f) {
    __hip_bfloat16 h = __float2bfloat16(f);   // RTNE
    return *reinterpret_cast<unsigned short*>(&h);
}

// ---------------- prep: W -> bf16 MFMA-fragment layout; cdiff = c0 - c1 ----
// wpre[ks][kgrp][leaf] : bf16x8 = W[leaf][ks*32+kgrp*8 .. +8), 0-padded tail
__global__ __launch_bounds__(256) void dn_prep(
    const float* __restrict__ W, const float* __restrict__ contrib,
    unsigned short* __restrict__ wpre, float* __restrict__ cdiff)
{
    const int gid = blockIdx.x * 256 + threadIdx.x;
    if (gid < WPRE_ELEMS) {
        const int leaf = gid & 255;
        const int kg   = (gid >> 8) & 3;
        const int ks   = gid >> 10;
        const int k0   = ks * BK + kg * 8;
        bf16x8 v;
        #pragma unroll
        for (int j = 0; j < 8; ++j) {
            const int k = k0 + j;
            const float f = (k < F_SZ) ? W[(size_t)leaf * F_SZ + k] : 0.f;
            v[j] = (short)f2bf(f);
        }
        *reinterpret_cast<bf16x8*>(wpre + (size_t)gid * 8) = v;
    } else {
        const int cid = gid - WPRE_ELEMS;
        if (cid < CDIFF_ELEMS)
            cdiff[cid] = contrib[(size_t)cid * 2] - contrib[(size_t)cid * 2 + 1];
    }
}

// ---------------- v6: whole-x-tile LDS staging, CONTIGUOUS global reads ----
// Block = 32 rows x 256 cols (grid 4096) -> x read from HBM exactly once.
// Staging phase: threads walk the 32x784 f32 tile FLAT, so every
// global_load_dwordx4 covers 1KB contiguous (16 cache lines — the coalescing
// ideal), fixing the 16-row-scattered loads that throttled v1–v5 (~32 lines
// per instruction -> TA-bound at ~1.5 TB/s).
// LDS layout As[kc][row ^ (kc&7)] (bf16x8 slots): XOR swizzle makes the
// staging ds_write_b128 8-deep (LDS-optimal) and the frag ds_read_b128
// conflict-free. One __syncthreads total; K-loop reads A from LDS and W from
// L2-resident prepacked wpre (contiguous 256B/16-lane reads), zero inner-loop
// format conversions.
__global__ __launch_bounds__(256, 3) void dn_fused6(
    const float* __restrict__ x, const unsigned short* __restrict__ wpre,
    const float* __restrict__ bias, const float* __restrict__ cdiff,
    float* __restrict__ out)
{
    __shared__ bf16x8 As[KCHUNKS * BROWS];   // 3200 slots = 51.2 KB

    const int tid  = threadIdx.x;
    const int lane = tid & 63;
    const int wid  = tid >> 6;          // 0..3 -> column group
    const int lr   = lane & 15;
    const int kseg = lane >> 4;         // 0..3

    const int rowBase = blockIdx.x * BROWS;
    const int colBase = wid * 64;

    // ---- stage x tile (32 rows x 784 f32 -> bf16 LDS), contiguous ----
    #pragma unroll
    for (int it = 0; it < 13; ++it) {
        const int i = it * 256 + tid;           // flat chunk id
        if (i < BROWS * KCHUNKS) {
            const int row = i / KCHUNKS;        // 0..31 (magic-mul)
            const int kc  = i - row * KCHUNKS;  // 0..99
            bf16x8 v;
            if (kc < 98) {                      // real data: k in [kc*8, kc*8+8)
                const float* p = x + (size_t)(rowBase + row) * F_SZ + kc * 8;
                const f32x4 lo = *reinterpret_cast<const f32x4*>(p);
                const f32x4 hi = *reinterpret_cast<const f32x4*>(p + 4);
                #pragma unroll
                for (int j = 0; j < 4; ++j) {
                    v[j]     = (short)f2bf(lo[j]);
                    v[4 + j] = (short)f2bf(hi[j]);
                }
            } else {                            // zero-pad k >= 784
                #pragma unroll
                for (int j = 0; j < 8; ++j) v[j] = 0;
            }
            As[kc * BROWS + (row ^ (kc & 7))] = v;
        }
    }
    __syncthreads();

    // ---- K-loop: A from LDS, W streamed from L2 (1-step lookahead) ----
    const unsigned short* wpb = wpre + ((size_t)kseg * L_SZ + colBase + lr) * 8;

    f32x4 acc[2][4];
    #pragma unroll
    for (int mi = 0; mi < 2; ++mi)
        #pragma unroll
        for (int ni = 0; ni < 4; ++ni)
            acc[mi][ni] = (f32x4){0.f, 0.f, 0.f, 0.f};

    bf16x8 wcur[4], wnxt[4];
    #pragma unroll
    for (int ni = 0; ni < 4; ++ni)
        wcur[ni] = *reinterpret_cast<const bf16x8*>(wpb + ni * 128);

    #pragma unroll
    for (int ks = 0; ks < KSTEPS; ++ks) {
        if (ks + 1 < KSTEPS) {
            #pragma unroll
            for (int ni = 0; ni < 4; ++ni)
                wnxt[ni] = *reinterpret_cast<const bf16x8*>(
                    wpb + (size_t)(ks + 1) * 8192 + ni * 128);
        }

        const int kcr = ks * 4 + kseg;          // k-chunk this lane consumes
        const bf16x8 a0 = As[kcr * BROWS + (lr ^ (kcr & 7))];
        const bf16x8 a1 = As[kcr * BROWS + ((16 + lr) ^ (kcr & 7))];

        #pragma unroll
        for (int ni = 0; ni < 4; ++ni) {
            acc[0][ni] = __builtin_amdgcn_mfma_f32_16x16x32_bf16(a0, wcur[ni], acc[0][ni], 0, 0, 0);
            acc[1][ni] = __builtin_amdgcn_mfma_f32_16x16x32_bf16(a1, wcur[ni], acc[1][ni], 0, 0, 0);
        }
        #pragma unroll
        for (int ni = 0; ni < 4; ++ni) wcur[ni] = wnxt[ni];
    }

    // epilogue: sp = clip(acc + b); gini = 1 + 2 s (1-s), s = sigmoid(sp*cdiff)
    const size_t GOFF = (size_t)M_TOT * L_SZ;
    #pragma unroll
    for (int ni = 0; ni < 4; ++ni) {
        const int col = colBase + ni * 16 + lr;
        const float bb = bias[col];
        #pragma unroll
        for (int mi = 0; mi < 2; ++mi) {
            #pragma unroll
            for (int r = 0; r < 4; ++r) {
                const int m = rowBase + mi * 16 + kseg * 4 + r;   // C/D row map
                const int t = m & (T_SZ - 1);
                float v  = acc[mi][ni][r] + bb;
                float sp = fminf(fmaxf(v, -1.f), 1.f);
                const float d  = sp * cdiff[t * L_SZ + col];
                const float ed = __expf(d);
                const float s2 = ed / (1.f + ed);
                const float g  = fmaf(2.f * s2, 1.f - s2, 1.f);
                const size_t o = (size_t)m * L_SZ + col;
                out[o]        = sp;
                out[GOFF + o] = g;
            }
        }
    }
}

// ---------------- v1 fallback (no workspace needed) ------------------------
__global__ __launch_bounds__(512) void dn_fused_v1(
    const float* __restrict__ x, const float* __restrict__ W,
    const float* __restrict__ bias, const float* __restrict__ contrib,
    float* __restrict__ out)
{
    __shared__ bf16x8 As[4][128];
    __shared__ bf16x8 Bs[4][L_SZ];

    const int tid    = threadIdx.x;
    const int lane   = tid & 63;
    const int wid    = tid >> 6;
    const int waveM  = wid >> 2;
    const int waveN  = wid & 3;
    const int blkRow = blockIdx.x * 128;
    const int ar = tid >> 2;
    const int ak = (tid & 3) * 8;
    const int wr = tid >> 1;
    const int wk = (tid & 1) * 16;
    const int laneRow = lane & 15;
    const int kgrp    = lane >> 4;

    f32x4 acc[4][4];
    #pragma unroll
    for (int i = 0; i < 4; ++i)
        #pragma unroll
        for (int j = 0; j < 4; ++j)
            acc[i][j] = (f32x4){0.f, 0.f, 0.f, 0.f};

    const float* xrow = x + (size_t)(blkRow + ar) * F_SZ;
    const float* wrow = W + (size_t)wr * F_SZ;
    const f32x4 zf = {0.f, 0.f, 0.f, 0.f};

    f32x4 xa0 = *reinterpret_cast<const f32x4*>(xrow + ak);
    f32x4 xa1 = *reinterpret_cast<const f32x4*>(xrow + ak + 4);
    f32x4 wa0 = *reinterpret_cast<const f32x4*>(wrow + wk);
    f32x4 wa1 = *reinterpret_cast<const f32x4*>(wrow + wk + 4);
    f32x4 wa2 = *reinterpret_cast<const f32x4*>(wrow + wk + 8);
    f32x4 wa3 = *reinterpret_cast<const f32x4*>(wrow + wk + 12);

    for (int ks = 0; ks < KSTEPS; ++ks) {
        bf16x8 av, wv0, wv1;
        #pragma unroll
        for (int j = 0; j < 4; ++j) {
            av[j]      = (short)f2bf(xa0[j]);
            av[4 + j]  = (short)f2bf(xa1[j]);
            wv0[j]     = (short)f2bf(wa0[j]);
            wv0[4 + j] = (short)f2bf(wa1[j]);
            wv1[j]     = (short)f2bf(wa2[j]);
            wv1[4 + j] = (short)f2bf(wa3[j]);
        }
        As[ak >> 3][ar] = av;
        Bs[wk >> 3][wr] = wv0;
        Bs[(wk >> 3) + 1][wr] = wv1;
        __syncthreads();

        if (ks + 1 < KSTEPS) {
            const int kb = (ks + 1) * BK;
            if (kb + ak < F_SZ) {
                xa0 = *reinterpret_cast<const f32x4*>(xrow + kb + ak);
                xa1 = *reinterpret_cast<const f32x4*>(xrow + kb + ak + 4);
            } else { xa0 = zf; xa1 = zf; }
            if (kb + wk < F_SZ) {
                wa0 = *reinterpret_cast<const f32x4*>(wrow + kb + wk);
                wa1 = *reinterpret_cast<const f32x4*>(wrow + kb + wk + 4);
                wa2 = *reinterpret_cast<const f32x4*>(wrow + kb + wk + 8);
                wa3 = *reinterpret_cast<const f32x4*>(wrow + kb + wk + 12);
            } else { wa0 = zf; wa1 = zf; wa2 = zf; wa3 = zf; }
        }

        bf16x8 af[4], bfv[4];
        #pragma unroll
        for (int mi = 0; mi < 4; ++mi)
            af[mi] = As[kgrp][waveM * 64 + mi * 16 + laneRow];
        #pragma unroll
        for (int ni = 0; ni < 4; ++ni)
            bfv[ni] = Bs[kgrp][waveN * 64 + ni * 16 + laneRow];
        #pragma unroll
        for (int mi = 0; mi < 4; ++mi)
            #pragma unroll
            for (int ni = 0; ni < 4; ++ni)
                acc[mi][ni] = __builtin_amdgcn_mfma_f32_16x16x32_bf16(
                    af[mi], bfv[ni], acc[mi][ni], 0, 0, 0);
        __syncthreads();
    }

    const size_t GOFF  = (size_t)M_TOT * L_SZ;
    const int    rbase = waveM * 64 + (lane >> 4) * 4;
    const int    cbase = waveN * 64 + laneRow;
    #pragma unroll
    for (int ni = 0; ni < 4; ++ni) {
        const int col = cbase + ni * 16;
        const float bb = bias[col];
        #pragma unroll
        for (int mi = 0; mi < 4; ++mi) {
            #pragma unroll
            for (int r = 0; r < 4; ++r) {
                const int m = blkRow + rbase + mi * 16 + r;
                const int t = m & (T_SZ - 1);
                float v  = acc[mi][ni][r] + bb;
                float sp = fminf(fmaxf(v, -1.f), 1.f);
                const float* cp = contrib + (size_t)(t * L_SZ + col) * 2;
                const float d  = sp * (cp[0] - cp[1]);
                const float ed = __expf(d);
                const float s  = ed / (1.f + ed);
                const float g  = fmaf(2.f * s, 1.f - s, 1.f);
                const size_t o = (size_t)m * L_SZ + col;
                out[o]        = sp;
                out[GOFF + o] = g;
            }
        }
    }
}

extern "C" void kernel_launch(void* const* d_in, const int* in_sizes, int n_in,
                              void* d_out, int out_size, void* d_ws, size_t ws_size,
                              hipStream_t stream) {
    const float* x       = (const float*)d_in[0];
    const float* W       = (const float*)d_in[1];
    const float* bias    = (const float*)d_in[2];
    const float* contrib = (const float*)d_in[3];
    float* out = (float*)d_out;

    if (ws_size >= (size_t)WS_NEED && d_ws != nullptr) {
        unsigned short* wpre  = (unsigned short*)d_ws;
        float*          cdiff = (float*)((char*)d_ws + WPRE_BYTES);
        const int prep_threads = WPRE_ELEMS + CDIFF_ELEMS;
        dn_prep<<<(prep_threads + 255) / 256, 256, 0, stream>>>(W, contrib, wpre, cdiff);
        dn_fused6<<<M_TOT / BROWS, 256, 0, stream>>>(x, wpre, bias, cdiff, out);
    } else {
        dn_fused_v1<<<M_TOT / 128, 512, 0, stream>>>(x, W, bias, contrib, out);
    }
}

// Round 8
// 186.489 us; speedup vs baseline: 1.8065x; 1.4576x over previous
//
#include <hip/hip_runtime.h>
#include <hip/hip_bf16.h>

typedef __attribute__((ext_vector_type(8))) short bf16x8;
typedef __attribute__((ext_vector_type(4))) float f32x4;

#define B_SZ   1024
#define T_SZ   128
#define L_SZ   256
#define F_SZ   784
#define M_TOT  (B_SZ * T_SZ)            // 131072
#define BK     32
#define KSTEPS 25                       // ceil(784/32), tail zero-padded
#define KCHUNKS 100                     // KSTEPS*4 chunks of 8 k-values
#define BROWS  32                       // rows per block

#define WPRE_ELEMS (KSTEPS * 4 * L_SZ)  // 25600 bf16x8 elements
#define WPRE_BYTES (WPRE_ELEMS * 16)    // 409600
#define CDIFF_ELEMS (T_SZ * L_SZ)       // 32768
#define WS_NEED (WPRE_BYTES + CDIFF_ELEMS * 4)

__device__ __forceinline__ unsigned short f2bf(float f) {
    __hip_bfloat16 h = __float2bfloat16(f);   // RTNE
    return *reinterpret_cast<unsigned short*>(&h);
}

// ---------------- prep: W -> bf16 MFMA-fragment layout; cdiff = c0 - c1 ----
// wpre[ks][kgrp][leaf] : bf16x8 = W[leaf][ks*32+kgrp*8 .. +8), 0-padded tail
__global__ __launch_bounds__(256) void dn_prep(
    const float* __restrict__ W, const float* __restrict__ contrib,
    unsigned short* __restrict__ wpre, float* __restrict__ cdiff)
{
    const int gid = blockIdx.x * 256 + threadIdx.x;
    if (gid < WPRE_ELEMS) {
        const int leaf = gid & 255;
        const int kg   = (gid >> 8) & 3;
        const int ks   = gid >> 10;
        const int k0   = ks * BK + kg * 8;
        bf16x8 v;
        #pragma unroll
        for (int j = 0; j < 8; ++j) {
            const int k = k0 + j;
            const float f = (k < F_SZ) ? W[(size_t)leaf * F_SZ + k] : 0.f;
            v[j] = (short)f2bf(f);
        }
        *reinterpret_cast<bf16x8*>(wpre + (size_t)gid * 8) = v;
    } else {
        const int cid = gid - WPRE_ELEMS;
        if (cid < CDIFF_ELEMS)
            cdiff[cid] = contrib[(size_t)cid * 2] - contrib[(size_t)cid * 2 + 1];
    }
}

// ---------------- v7: v6 staging + 512 thr (24 waves/CU) + LDS-transpose ---
// epilogue with full-line contiguous stores.
// Block = 32 rows x 256 cols, 8 waves (wave tile 32 rows x 32 cols).
// LDS (51.2 KB, 3 blocks/CU): As[kc][row^(kc&7)] bf16x8 during GEMM, then
// reused (barrier-separated) as float Ot[32][264] for the output transpose.
__global__ __launch_bounds__(512, 6) void dn_fused7(
    const float* __restrict__ x, const unsigned short* __restrict__ wpre,
    const float* __restrict__ bias, const float* __restrict__ cdiff,
    float* __restrict__ out)
{
    __shared__ __align__(16) unsigned char smem[KCHUNKS * BROWS * 16]; // 51.2 KB
    bf16x8* As = reinterpret_cast<bf16x8*>(smem);
    typedef float OtRow[264];                    // 264 pad: 16B-aligned rows,
    OtRow* Ot = reinterpret_cast<OtRow*>(smem);  // +8 bank rotation/row

    const int tid  = threadIdx.x;
    const int lane = tid & 63;
    const int wid  = tid >> 6;          // 0..7 -> 32-col group
    const int lr   = lane & 15;
    const int kseg = lane >> 4;         // 0..3

    const int rowBase = blockIdx.x * BROWS;
    const int colBase = wid * 32;

    // ---- stage x tile (32 x 784 f32 -> bf16 LDS), contiguous reads ----
    #pragma unroll
    for (int it = 0; it < 7; ++it) {
        const int i = it * 512 + tid;           // flat chunk id
        if (i < BROWS * KCHUNKS) {
            const int row = i / KCHUNKS;        // 0..31
            const int kc  = i - row * KCHUNKS;  // 0..99
            bf16x8 v;
            if (kc < 98) {                      // k in [kc*8, kc*8+8)
                const float* p = x + (size_t)(rowBase + row) * F_SZ + kc * 8;
                const f32x4 lo = *reinterpret_cast<const f32x4*>(p);
                const f32x4 hi = *reinterpret_cast<const f32x4*>(p + 4);
                #pragma unroll
                for (int j = 0; j < 4; ++j) {
                    v[j]     = (short)f2bf(lo[j]);
                    v[4 + j] = (short)f2bf(hi[j]);
                }
            } else {                            // zero-pad k >= 784
                #pragma unroll
                for (int j = 0; j < 8; ++j) v[j] = 0;
            }
            As[kc * BROWS + (row ^ (kc & 7))] = v;
        }
    }
    __syncthreads();

    // ---- K-loop: A from LDS, W streamed from L2 (1-step lookahead) ----
    const unsigned short* wpb = wpre + ((size_t)kseg * L_SZ + colBase + lr) * 8;

    f32x4 acc[2][2];
    #pragma unroll
    for (int mi = 0; mi < 2; ++mi)
        #pragma unroll
        for (int ni = 0; ni < 2; ++ni)
            acc[mi][ni] = (f32x4){0.f, 0.f, 0.f, 0.f};

    bf16x8 wcur[2], wnxt[2];
    wcur[0] = *reinterpret_cast<const bf16x8*>(wpb);
    wcur[1] = *reinterpret_cast<const bf16x8*>(wpb + 128);

    #pragma unroll
    for (int ks = 0; ks < KSTEPS; ++ks) {
        if (ks + 1 < KSTEPS) {
            wnxt[0] = *reinterpret_cast<const bf16x8*>(wpb + (size_t)(ks + 1) * 8192);
            wnxt[1] = *reinterpret_cast<const bf16x8*>(wpb + (size_t)(ks + 1) * 8192 + 128);
        }
        const int kcr = ks * 4 + kseg;
        const bf16x8 a0 = As[kcr * BROWS + (lr ^ (kcr & 7))];
        const bf16x8 a1 = As[kcr * BROWS + ((16 + lr) ^ (kcr & 7))];

        acc[0][0] = __builtin_amdgcn_mfma_f32_16x16x32_bf16(a0, wcur[0], acc[0][0], 0, 0, 0);
        acc[0][1] = __builtin_amdgcn_mfma_f32_16x16x32_bf16(a0, wcur[1], acc[0][1], 0, 0, 0);
        acc[1][0] = __builtin_amdgcn_mfma_f32_16x16x32_bf16(a1, wcur[0], acc[1][0], 0, 0, 0);
        acc[1][1] = __builtin_amdgcn_mfma_f32_16x16x32_bf16(a1, wcur[1], acc[1][1], 0, 0, 0);

        wcur[0] = wnxt[0];
        wcur[1] = wnxt[1];
    }
    __syncthreads();   // all As reads done; smem becomes Ot

    // ---- sp in registers ----
    float spv[2][2][4];
    #pragma unroll
    for (int ni = 0; ni < 2; ++ni) {
        const float bb = bias[colBase + ni * 16 + lr];
        #pragma unroll
        for (int mi = 0; mi < 2; ++mi)
            #pragma unroll
            for (int r = 0; r < 4; ++r)
                spv[mi][ni][r] = fminf(fmaxf(acc[mi][ni][r] + bb, -1.f), 1.f);
    }

    const int erow = tid >> 4;          // 0..31
    const int ecol = (tid & 15) * 4;    // 0..60 (x4-float chunks)
    const size_t GOFF = (size_t)M_TOT * L_SZ;
    float* orow = out + (size_t)(rowBase + erow) * L_SZ;

    // ---- pass 1: sp -> LDS transpose -> contiguous store ----
    #pragma unroll
    for (int ni = 0; ni < 2; ++ni)
        #pragma unroll
        for (int mi = 0; mi < 2; ++mi)
            #pragma unroll
            for (int r = 0; r < 4; ++r)
                Ot[mi * 16 + kseg * 4 + r][colBase + ni * 16 + lr] = spv[mi][ni][r];
    __syncthreads();
    #pragma unroll
    for (int j = 0; j < 4; ++j) {
        const f32x4 v = *reinterpret_cast<const f32x4*>(&Ot[erow][ecol + 64 * j]);
        *reinterpret_cast<f32x4*>(orow + ecol + 64 * j) = v;
    }
    __syncthreads();

    // ---- pass 2: gini -> LDS transpose -> contiguous store ----
    #pragma unroll
    for (int ni = 0; ni < 2; ++ni) {
        const int col = colBase + ni * 16 + lr;
        #pragma unroll
        for (int mi = 0; mi < 2; ++mi)
            #pragma unroll
            for (int r = 0; r < 4; ++r) {
                const int t = (rowBase + mi * 16 + kseg * 4 + r) & (T_SZ - 1);
                const float d  = spv[mi][ni][r] * cdiff[t * L_SZ + col];
                const float ed = __expf(d);
                const float s2 = ed / (1.f + ed);
                Ot[mi * 16 + kseg * 4 + r][col] = fmaf(2.f * s2, 1.f - s2, 1.f);
            }
    }
    __syncthreads();
    #pragma unroll
    for (int j = 0; j < 4; ++j) {
        const f32x4 v = *reinterpret_cast<const f32x4*>(&Ot[erow][ecol + 64 * j]);
        *reinterpret_cast<f32x4*>(orow + GOFF + ecol + 64 * j) = v;
    }
}

// ---------------- v1 fallback (no workspace needed) ------------------------
__global__ __launch_bounds__(512) void dn_fused_v1(
    const float* __restrict__ x, const float* __restrict__ W,
    const float* __restrict__ bias, const float* __restrict__ contrib,
    float* __restrict__ out)
{
    __shared__ bf16x8 As[4][128];
    __shared__ bf16x8 Bs[4][L_SZ];

    const int tid    = threadIdx.x;
    const int lane   = tid & 63;
    const int wid    = tid >> 6;
    const int waveM  = wid >> 2;
    const int waveN  = wid & 3;
    const int blkRow = blockIdx.x * 128;
    const int ar = tid >> 2;
    const int ak = (tid & 3) * 8;
    const int wr = tid >> 1;
    const int wk = (tid & 1) * 16;
    const int laneRow = lane & 15;
    const int kgrp    = lane >> 4;

    f32x4 acc[4][4];
    #pragma unroll
    for (int i = 0; i < 4; ++i)
        #pragma unroll
        for (int j = 0; j < 4; ++j)
            acc[i][j] = (f32x4){0.f, 0.f, 0.f, 0.f};

    const float* xrow = x + (size_t)(blkRow + ar) * F_SZ;
    const float* wrow = W + (size_t)wr * F_SZ;
    const f32x4 zf = {0.f, 0.f, 0.f, 0.f};

    f32x4 xa0 = *reinterpret_cast<const f32x4*>(xrow + ak);
    f32x4 xa1 = *reinterpret_cast<const f32x4*>(xrow + ak + 4);
    f32x4 wa0 = *reinterpret_cast<const f32x4*>(wrow + wk);
    f32x4 wa1 = *reinterpret_cast<const f32x4*>(wrow + wk + 4);
    f32x4 wa2 = *reinterpret_cast<const f32x4*>(wrow + wk + 8);
    f32x4 wa3 = *reinterpret_cast<const f32x4*>(wrow + wk + 12);

    for (int ks = 0; ks < KSTEPS; ++ks) {
        bf16x8 av, wv0, wv1;
        #pragma unroll
        for (int j = 0; j < 4; ++j) {
            av[j]      = (short)f2bf(xa0[j]);
            av[4 + j]  = (short)f2bf(xa1[j]);
            wv0[j]     = (short)f2bf(wa0[j]);
            wv0[4 + j] = (short)f2bf(wa1[j]);
            wv1[j]     = (short)f2bf(wa2[j]);
            wv1[4 + j] = (short)f2bf(wa3[j]);
        }
        As[ak >> 3][ar] = av;
        Bs[wk >> 3][wr] = wv0;
        Bs[(wk >> 3) + 1][wr] = wv1;
        __syncthreads();

        if (ks + 1 < KSTEPS) {
            const int kb = (ks + 1) * BK;
            if (kb + ak < F_SZ) {
                xa0 = *reinterpret_cast<const f32x4*>(xrow + kb + ak);
                xa1 = *reinterpret_cast<const f32x4*>(xrow + kb + ak + 4);
            } else { xa0 = zf; xa1 = zf; }
            if (kb + wk < F_SZ) {
                wa0 = *reinterpret_cast<const f32x4*>(wrow + kb + wk);
                wa1 = *reinterpret_cast<const f32x4*>(wrow + kb + wk + 4);
                wa2 = *reinterpret_cast<const f32x4*>(wrow + kb + wk + 8);
                wa3 = *reinterpret_cast<const f32x4*>(wrow + kb + wk + 12);
            } else { wa0 = zf; wa1 = zf; wa2 = zf; wa3 = zf; }
        }

        bf16x8 af[4], bfv[4];
        #pragma unroll
        for (int mi = 0; mi < 4; ++mi)
            af[mi] = As[kgrp][waveM * 64 + mi * 16 + laneRow];
        #pragma unroll
        for (int ni = 0; ni < 4; ++ni)
            bfv[ni] = Bs[kgrp][waveN * 64 + ni * 16 + laneRow];
        #pragma unroll
        for (int mi = 0; mi < 4; ++mi)
            #pragma unroll
            for (int ni = 0; ni < 4; ++ni)
                acc[mi][ni] = __builtin_amdgcn_mfma_f32_16x16x32_bf16(
                    af[mi], bfv[ni], acc[mi][ni], 0, 0, 0);
        __syncthreads();
    }

    const size_t GOFF  = (size_t)M_TOT * L_SZ;
    const int    rbase = waveM * 64 + (lane >> 4) * 4;
    const int    cbase = waveN * 64 + laneRow;
    #pragma unroll
    for (int ni = 0; ni < 4; ++ni) {
        const int col = cbase + ni * 16;
        const float bb = bias[col];
        #pragma unroll
        for (int mi = 0; mi < 4; ++mi) {
            #pragma unroll
            for (int r = 0; r < 4; ++r) {
                const int m = blkRow + rbase + mi * 16 + r;
                const int t = m & (T_SZ - 1);
                float v  = acc[mi][ni][r] + bb;
                float sp = fminf(fmaxf(v, -1.f), 1.f);
                const float* cp = contrib + (size_t)(t * L_SZ + col) * 2;
                const float d  = sp * (cp[0] - cp[1]);
                const float ed = __expf(d);
                const float s  = ed / (1.f + ed);
                const float g  = fmaf(2.f * s, 1.f - s, 1.f);
                const size_t o = (size_t)m * L_SZ + col;
                out[o]        = sp;
                out[GOFF + o] = g;
            }
        }
    }
}

extern "C" void kernel_launch(void* const* d_in, const int* in_sizes, int n_in,
                              void* d_out, int out_size, void* d_ws, size_t ws_size,
                              hipStream_t stream) {
    const float* x       = (const float*)d_in[0];
    const float* W       = (const float*)d_in[1];
    const float* bias    = (const float*)d_in[2];
    const float* contrib = (const float*)d_in[3];
    float* out = (float*)d_out;

    if (ws_size >= (size_t)WS_NEED && d_ws != nullptr) {
        unsigned short* wpre  = (unsigned short*)d_ws;
        float*          cdiff = (float*)((char*)d_ws + WPRE_BYTES);
        const int prep_threads = WPRE_ELEMS + CDIFF_ELEMS;
        dn_prep<<<(prep_threads + 255) / 256, 256, 0, stream>>>(W, contrib, wpre, cdiff);
        dn_fused7<<<M_TOT / BROWS, 512, 0, stream>>>(x, wpre, bias, cdiff, out);
    } else {
        dn_fused_v1<<<M_TOT / 128, 512, 0, stream>>>(x, W, bias, contrib, out);
    }
}

// Round 9
// 178.839 us; speedup vs baseline: 1.8838x; 1.0428x over previous
//
#include <hip/hip_runtime.h>
#include <hip/hip_bf16.h>

typedef __attribute__((ext_vector_type(8))) short bf16x8;
typedef __attribute__((ext_vector_type(4))) float f32x4;

#define B_SZ   1024
#define T_SZ   128
#define L_SZ   256
#define F_SZ   784
#define M_TOT  (B_SZ * T_SZ)            // 131072
#define BK     32
#define KSTEPS 25                       // ceil(784/32), tail zero-padded
#define KCHUNKS 100                     // KSTEPS*4 chunks of 8 k-values
#define BROWS  32                       // rows per block

#define WPRE_ELEMS (KSTEPS * 4 * L_SZ)  // 25600 bf16x8 elements
#define WPRE_BYTES (WPRE_ELEMS * 16)    // 409600
#define CDIFF_ELEMS (T_SZ * L_SZ)       // 32768
#define WS_NEED (WPRE_BYTES + CDIFF_ELEMS * 4)

__device__ __forceinline__ unsigned short f2bf(float f) {
    __hip_bfloat16 h = __float2bfloat16(f);   // RTNE
    return *reinterpret_cast<unsigned short*>(&h);
}

// ---------------- prep: W -> bf16 MFMA-fragment layout; cdiff = c0 - c1 ----
// wpre[ks][kgrp][leaf] : bf16x8 = W[leaf][ks*32+kgrp*8 .. +8), 0-padded tail
__global__ __launch_bounds__(256) void dn_prep(
    const float* __restrict__ W, const float* __restrict__ contrib,
    unsigned short* __restrict__ wpre, float* __restrict__ cdiff)
{
    const int gid = blockIdx.x * 256 + threadIdx.x;
    if (gid < WPRE_ELEMS) {
        const int leaf = gid & 255;
        const int kg   = (gid >> 8) & 3;
        const int ks   = gid >> 10;
        const int k0   = ks * BK + kg * 8;
        bf16x8 v;
        #pragma unroll
        for (int j = 0; j < 8; ++j) {
            const int k = k0 + j;
            const float f = (k < F_SZ) ? W[(size_t)leaf * F_SZ + k] : 0.f;
            v[j] = (short)f2bf(f);
        }
        *reinterpret_cast<bf16x8*>(wpre + (size_t)gid * 8) = v;
    } else {
        const int cid = gid - WPRE_ELEMS;
        if (cid < CDIFF_ELEMS)
            cdiff[cid] = contrib[(size_t)cid * 2] - contrib[(size_t)cid * 2 + 1];
    }
}

// ---------------- v8: v7 structure at 1024 thr -> 32 waves/CU (100%) -------
// Block = 32 rows x 256 cols, 16 waves, wave tile 32 rows x 16 cols
// (2 MFMA + 2 LDS A-reads + 1 W-load per K-step). Same 51.2 KB LDS ->
// 2 blocks/CU; wave slots 24 -> 32 per CU for deeper phase overlap.
__global__ __launch_bounds__(1024, 2) void dn_fused8(
    const float* __restrict__ x, const unsigned short* __restrict__ wpre,
    const float* __restrict__ bias, const float* __restrict__ cdiff,
    float* __restrict__ out)
{
    __shared__ __align__(16) unsigned char smem[KCHUNKS * BROWS * 16]; // 51.2 KB
    bf16x8* As = reinterpret_cast<bf16x8*>(smem);
    typedef float OtRow[264];                    // +8 pad: bank rotation/row
    OtRow* Ot = reinterpret_cast<OtRow*>(smem);

    const int tid  = threadIdx.x;
    const int lane = tid & 63;
    const int wid  = tid >> 6;          // 0..15 -> 16-col group
    const int lr   = lane & 15;
    const int kseg = lane >> 4;         // 0..3

    const int rowBase = blockIdx.x * BROWS;
    const int colBase = wid * 16;

    // ---- stage x tile (32 x 784 f32 -> bf16 LDS), contiguous reads ----
    #pragma unroll
    for (int it = 0; it < 4; ++it) {
        const int i = it * 1024 + tid;          // flat chunk id
        if (i < BROWS * KCHUNKS) {
            const int row = i / KCHUNKS;        // 0..31
            const int kc  = i - row * KCHUNKS;  // 0..99
            bf16x8 v;
            if (kc < 98) {                      // k in [kc*8, kc*8+8)
                const float* p = x + (size_t)(rowBase + row) * F_SZ + kc * 8;
                const f32x4 lo = *reinterpret_cast<const f32x4*>(p);
                const f32x4 hi = *reinterpret_cast<const f32x4*>(p + 4);
                #pragma unroll
                for (int j = 0; j < 4; ++j) {
                    v[j]     = (short)f2bf(lo[j]);
                    v[4 + j] = (short)f2bf(hi[j]);
                }
            } else {                            // zero-pad k >= 784
                #pragma unroll
                for (int j = 0; j < 8; ++j) v[j] = 0;
            }
            As[kc * BROWS + (row ^ (kc & 7))] = v;
        }
    }
    __syncthreads();

    // ---- K-loop: A from LDS, W streamed from L2 (1-step lookahead) ----
    const unsigned short* wpb = wpre + ((size_t)kseg * L_SZ + colBase + lr) * 8;

    f32x4 acc[2];
    acc[0] = (f32x4){0.f, 0.f, 0.f, 0.f};
    acc[1] = (f32x4){0.f, 0.f, 0.f, 0.f};

    bf16x8 wcur = *reinterpret_cast<const bf16x8*>(wpb);
    bf16x8 wnxt;

    #pragma unroll
    for (int ks = 0; ks < KSTEPS; ++ks) {
        if (ks + 1 < KSTEPS)
            wnxt = *reinterpret_cast<const bf16x8*>(wpb + (size_t)(ks + 1) * 8192);

        const int kcr = ks * 4 + kseg;
        const bf16x8 a0 = As[kcr * BROWS + (lr ^ (kcr & 7))];
        const bf16x8 a1 = As[kcr * BROWS + ((16 + lr) ^ (kcr & 7))];

        acc[0] = __builtin_amdgcn_mfma_f32_16x16x32_bf16(a0, wcur, acc[0], 0, 0, 0);
        acc[1] = __builtin_amdgcn_mfma_f32_16x16x32_bf16(a1, wcur, acc[1], 0, 0, 0);
        wcur = wnxt;
    }
    __syncthreads();   // all As reads done; smem becomes Ot

    // ---- sp in registers ----
    float spv[2][4];
    const float bb = bias[colBase + lr];
    #pragma unroll
    for (int mi = 0; mi < 2; ++mi)
        #pragma unroll
        for (int r = 0; r < 4; ++r)
            spv[mi][r] = fminf(fmaxf(acc[mi][r] + bb, -1.f), 1.f);

    const int erow = tid >> 5;          // 0..31
    const int ecol = (tid & 31) * 4;    // 0..124 (f32x4 chunks)
    const size_t GOFF = (size_t)M_TOT * L_SZ;
    float* orow = out + (size_t)(rowBase + erow) * L_SZ;

    // ---- pass 1: sp -> LDS transpose -> contiguous store ----
    #pragma unroll
    for (int mi = 0; mi < 2; ++mi)
        #pragma unroll
        for (int r = 0; r < 4; ++r)
            Ot[mi * 16 + kseg * 4 + r][colBase + lr] = spv[mi][r];
    __syncthreads();
    #pragma unroll
    for (int j = 0; j < 2; ++j) {
        const f32x4 v = *reinterpret_cast<const f32x4*>(&Ot[erow][ecol + 128 * j]);
        *reinterpret_cast<f32x4*>(orow + ecol + 128 * j) = v;
    }
    __syncthreads();

    // ---- pass 2: gini -> LDS transpose -> contiguous store ----
    {
        const int col = colBase + lr;
        #pragma unroll
        for (int mi = 0; mi < 2; ++mi)
            #pragma unroll
            for (int r = 0; r < 4; ++r) {
                const int t = (rowBase + mi * 16 + kseg * 4 + r) & (T_SZ - 1);
                const float d  = spv[mi][r] * cdiff[t * L_SZ + col];
                const float ed = __expf(d);
                const float s2 = ed / (1.f + ed);
                Ot[mi * 16 + kseg * 4 + r][col] = fmaf(2.f * s2, 1.f - s2, 1.f);
            }
    }
    __syncthreads();
    #pragma unroll
    for (int j = 0; j < 2; ++j) {
        const f32x4 v = *reinterpret_cast<const f32x4*>(&Ot[erow][ecol + 128 * j]);
        *reinterpret_cast<f32x4*>(orow + GOFF + ecol + 128 * j) = v;
    }
}

// ---------------- v1 fallback (no workspace needed) ------------------------
__global__ __launch_bounds__(512) void dn_fused_v1(
    const float* __restrict__ x, const float* __restrict__ W,
    const float* __restrict__ bias, const float* __restrict__ contrib,
    float* __restrict__ out)
{
    __shared__ bf16x8 As[4][128];
    __shared__ bf16x8 Bs[4][L_SZ];

    const int tid    = threadIdx.x;
    const int lane   = tid & 63;
    const int wid    = tid >> 6;
    const int waveM  = wid >> 2;
    const int waveN  = wid & 3;
    const int blkRow = blockIdx.x * 128;
    const int ar = tid >> 2;
    const int ak = (tid & 3) * 8;
    const int wr = tid >> 1;
    const int wk = (tid & 1) * 16;
    const int laneRow = lane & 15;
    const int kgrp    = lane >> 4;

    f32x4 acc[4][4];
    #pragma unroll
    for (int i = 0; i < 4; ++i)
        #pragma unroll
        for (int j = 0; j < 4; ++j)
            acc[i][j] = (f32x4){0.f, 0.f, 0.f, 0.f};

    const float* xrow = x + (size_t)(blkRow + ar) * F_SZ;
    const float* wrow = W + (size_t)wr * F_SZ;
    const f32x4 zf = {0.f, 0.f, 0.f, 0.f};

    f32x4 xa0 = *reinterpret_cast<const f32x4*>(xrow + ak);
    f32x4 xa1 = *reinterpret_cast<const f32x4*>(xrow + ak + 4);
    f32x4 wa0 = *reinterpret_cast<const f32x4*>(wrow + wk);
    f32x4 wa1 = *reinterpret_cast<const f32x4*>(wrow + wk + 4);
    f32x4 wa2 = *reinterpret_cast<const f32x4*>(wrow + wk + 8);
    f32x4 wa3 = *reinterpret_cast<const f32x4*>(wrow + wk + 12);

    for (int ks = 0; ks < KSTEPS; ++ks) {
        bf16x8 av, wv0, wv1;
        #pragma unroll
        for (int j = 0; j < 4; ++j) {
            av[j]      = (short)f2bf(xa0[j]);
            av[4 + j]  = (short)f2bf(xa1[j]);
            wv0[j]     = (short)f2bf(wa0[j]);
            wv0[4 + j] = (short)f2bf(wa1[j]);
            wv1[j]     = (short)f2bf(wa2[j]);
            wv1[4 + j] = (short)f2bf(wa3[j]);
        }
        As[ak >> 3][ar] = av;
        Bs[wk >> 3][wr] = wv0;
        Bs[(wk >> 3) + 1][wr] = wv1;
        __syncthreads();

        if (ks + 1 < KSTEPS) {
            const int kb = (ks + 1) * BK;
            if (kb + ak < F_SZ) {
                xa0 = *reinterpret_cast<const f32x4*>(xrow + kb + ak);
                xa1 = *reinterpret_cast<const f32x4*>(xrow + kb + ak + 4);
            } else { xa0 = zf; xa1 = zf; }
            if (kb + wk < F_SZ) {
                wa0 = *reinterpret_cast<const f32x4*>(wrow + kb + wk);
                wa1 = *reinterpret_cast<const f32x4*>(wrow + kb + wk + 4);
                wa2 = *reinterpret_cast<const f32x4*>(wrow + kb + wk + 8);
                wa3 = *reinterpret_cast<const f32x4*>(wrow + kb + wk + 12);
            } else { wa0 = zf; wa1 = zf; wa2 = zf; wa3 = zf; }
        }

        bf16x8 af[4], bfv[4];
        #pragma unroll
        for (int mi = 0; mi < 4; ++mi)
            af[mi] = As[kgrp][waveM * 64 + mi * 16 + laneRow];
        #pragma unroll
        for (int ni = 0; ni < 4; ++ni)
            bfv[ni] = Bs[kgrp][waveN * 64 + ni * 16 + laneRow];
        #pragma unroll
        for (int mi = 0; mi < 4; ++mi)
            #pragma unroll
            for (int ni = 0; ni < 4; ++ni)
                acc[mi][ni] = __builtin_amdgcn_mfma_f32_16x16x32_bf16(
                    af[mi], bfv[ni], acc[mi][ni], 0, 0, 0);
        __syncthreads();
    }

    const size_t GOFF  = (size_t)M_TOT * L_SZ;
    const int    rbase = waveM * 64 + (lane >> 4) * 4;
    const int    cbase = waveN * 64 + laneRow;
    #pragma unroll
    for (int ni = 0; ni < 4; ++ni) {
        const int col = cbase + ni * 16;
        const float bb = bias[col];
        #pragma unroll
        for (int mi = 0; mi < 4; ++mi) {
            #pragma unroll
            for (int r = 0; r < 4; ++r) {
                const int m = blkRow + rbase + mi * 16 + r;
                const int t = m & (T_SZ - 1);
                float v  = acc[mi][ni][r] + bb;
                float sp = fminf(fmaxf(v, -1.f), 1.f);
                const float* cp = contrib + (size_t)(t * L_SZ + col) * 2;
                const float d  = sp * (cp[0] - cp[1]);
                const float ed = __expf(d);
                const float s  = ed / (1.f + ed);
                const float g  = fmaf(2.f * s, 1.f - s, 1.f);
                const size_t o = (size_t)m * L_SZ + col;
                out[o]        = sp;
                out[GOFF + o] = g;
            }
        }
    }
}

extern "C" void kernel_launch(void* const* d_in, const int* in_sizes, int n_in,
                              void* d_out, int out_size, void* d_ws, size_t ws_size,
                              hipStream_t stream) {
    const float* x       = (const float*)d_in[0];
    const float* W       = (const float*)d_in[1];
    const float* bias    = (const float*)d_in[2];
    const float* contrib = (const float*)d_in[3];
    float* out = (float*)d_out;

    if (ws_size >= (size_t)WS_NEED && d_ws != nullptr) {
        unsigned short* wpre  = (unsigned short*)d_ws;
        float*          cdiff = (float*)((char*)d_ws + WPRE_BYTES);
        const int prep_threads = WPRE_ELEMS + CDIFF_ELEMS;
        dn_prep<<<(prep_threads + 255) / 256, 256, 0, stream>>>(W, contrib, wpre, cdiff);
        dn_fused8<<<M_TOT / BROWS, 1024, 0, stream>>>(x, wpre, bias, cdiff, out);
    } else {
        dn_fused_v1<<<M_TOT / 128, 512, 0, stream>>>(x, W, bias, contrib, out);
    }
}